// Round 1
// baseline (2053.717 us; speedup 1.0000x reference)
//
#include <hip/hip_runtime.h>

// ---------------------------------------------------------------------------
// GCN stack: 9 layers of  h = relu( Â (h W) + b ),  Â = D^-1/2 (A+I) D^-1/2
// Key identities used:
//   * Â(HW) == (ÂH)W  -> aggregate at width min(din,dout) per layer
//   * Â is the same for all layers -> build CSR once per launch
// All fp32 this round (correctness anchor).
// ---------------------------------------------------------------------------

#define NNODES 50000
#define TPB 256

// ---------------- graph prep kernels ----------------

__global__ void zero_int_kernel(int* p, int n) {
    int i = blockIdx.x * blockDim.x + threadIdx.x;
    if (i < n) p[i] = 0;
}

__global__ void count_kernel(const int* __restrict__ dst, int* __restrict__ cnt, int E) {
    int e = blockIdx.x * blockDim.x + threadIdx.x;
    if (e < E) atomicAdd(&cnt[dst[e]], 1);
}

__global__ void dinv_kernel(const int* __restrict__ cnt, float* __restrict__ dinv, int n) {
    int i = blockIdx.x * blockDim.x + threadIdx.x;
    if (i < n) dinv[i] = rsqrtf((float)(cnt[i] + 1));   // +1 self loop, deg>=1
}

// inclusive block scan -> exclusive output, block sums out
__global__ void scan1_kernel(const int* __restrict__ cnt, int* __restrict__ rowp,
                             int* __restrict__ bsums, int n) {
    __shared__ int sh[TPB];
    int t = threadIdx.x;
    int i = blockIdx.x * TPB + t;
    int v = (i < n) ? cnt[i] : 0;
    sh[t] = v;
    __syncthreads();
    for (int off = 1; off < TPB; off <<= 1) {
        int x = (t >= off) ? sh[t - off] : 0;
        __syncthreads();
        sh[t] += x;
        __syncthreads();
    }
    if (i < n) rowp[i] = sh[t] - v;          // exclusive
    if (t == TPB - 1) bsums[blockIdx.x] = sh[t];
}

__global__ void scan2_kernel(int* __restrict__ bsums, int nb) {
    __shared__ int sh[TPB];
    int t = threadIdx.x;
    int v = (t < nb) ? bsums[t] : 0;
    sh[t] = v;
    __syncthreads();
    for (int off = 1; off < TPB; off <<= 1) {
        int x = (t >= off) ? sh[t - off] : 0;
        __syncthreads();
        sh[t] += x;
        __syncthreads();
    }
    if (t < nb) bsums[t] = sh[t] - v;        // exclusive block offsets
}

__global__ void scan3_kernel(int* __restrict__ rowp, const int* __restrict__ bsums, int n) {
    int i = blockIdx.x * TPB + threadIdx.x;
    if (i < n) rowp[i] += bsums[blockIdx.x];
}

__global__ void fill_kernel(const int* __restrict__ src, const int* __restrict__ dst,
                            const float* __restrict__ dinv,
                            const int* __restrict__ rowp, int* __restrict__ fill,
                            int* __restrict__ csrc, float* __restrict__ cw, int E) {
    int e = blockIdx.x * blockDim.x + threadIdx.x;
    if (e >= E) return;
    int s = src[e], d = dst[e];
    int pos = rowp[d] + atomicAdd(&fill[d], 1);
    csrc[pos] = s;
    cw[pos] = dinv[s] * dinv[d];
}

// ---------------- dense kernels ----------------

// C[M,Nc] = A[M,K] @ B[K,Nc]  (+bias, relu)   K%16==0, Nc%64==0
__global__ __launch_bounds__(256) void gemm_kernel(
    const float* __restrict__ A, const float* __restrict__ B,
    const float* __restrict__ bias, float* __restrict__ C,
    int M, int K, int Nc, int doBias, int doRelu) {
    __shared__ float As[16][65];
    __shared__ float Bs[16][65];
    int t = threadIdx.x;
    int tx = t & 15, ty = t >> 4;
    int row0 = blockIdx.y * 64;
    int col0 = blockIdx.x * 64;

    float acc[4][4];
#pragma unroll
    for (int i = 0; i < 4; i++)
#pragma unroll
        for (int j = 0; j < 4; j++) acc[i][j] = 0.f;

    int aRow = t >> 2;               // 0..63
    int aCol4 = (t & 3) * 4;         // 0,4,8,12
    int bRow = t >> 4;               // 0..15
    int bCol4 = (t & 15) * 4;        // 0..60

    for (int k0 = 0; k0 < K; k0 += 16) {
        // load A tile (64x16) transposed into As[k][m]
        int gr = row0 + aRow;
        float4 av;
        if (gr < M) av = *(const float4*)(A + (size_t)gr * K + k0 + aCol4);
        else av = make_float4(0.f, 0.f, 0.f, 0.f);
        As[aCol4 + 0][aRow] = av.x;
        As[aCol4 + 1][aRow] = av.y;
        As[aCol4 + 2][aRow] = av.z;
        As[aCol4 + 3][aRow] = av.w;
        // load B tile (16x64)
        float4 bv = *(const float4*)(B + (size_t)(k0 + bRow) * Nc + col0 + bCol4);
        Bs[bRow][bCol4 + 0] = bv.x;
        Bs[bRow][bCol4 + 1] = bv.y;
        Bs[bRow][bCol4 + 2] = bv.z;
        Bs[bRow][bCol4 + 3] = bv.w;
        __syncthreads();
#pragma unroll
        for (int kk = 0; kk < 16; kk++) {
            float a[4], b[4];
#pragma unroll
            for (int i = 0; i < 4; i++) a[i] = As[kk][ty * 4 + i];
#pragma unroll
            for (int j = 0; j < 4; j++) b[j] = Bs[kk][tx * 4 + j];
#pragma unroll
            for (int i = 0; i < 4; i++)
#pragma unroll
                for (int j = 0; j < 4; j++) acc[i][j] += a[i] * b[j];
        }
        __syncthreads();
    }

#pragma unroll
    for (int i = 0; i < 4; i++) {
        int gr = row0 + ty * 4 + i;
        if (gr >= M) continue;
        float4 v;
        float* pv = &v.x;
#pragma unroll
        for (int j = 0; j < 4; j++) {
            float x = acc[i][j];
            if (doBias) x += bias[col0 + tx * 4 + j];
            if (doRelu) x = fmaxf(x, 0.f);
            pv[j] = x;
        }
        *(float4*)(C + (size_t)gr * Nc + col0 + tx * 4) = v;
    }
}

// out[m] = dot(A[m,0:128], w[0:128])   (one wave per row)
__global__ void gemv128_kernel(const float* __restrict__ A, const float* __restrict__ w,
                               float* __restrict__ out, int M) {
    int wid = (blockIdx.x * blockDim.x + threadIdx.x) >> 6;
    int lane = threadIdx.x & 63;
    if (wid >= M) return;
    const float* a = A + (size_t)wid * 128;
    float s = a[lane] * w[lane] + a[lane + 64] * w[lane + 64];
#pragma unroll
    for (int off = 32; off > 0; off >>= 1) s += __shfl_down(s, off);
    if (lane == 0) out[wid] = s;
}

// ---------------- aggregation kernels ----------------

// one block per node, blockDim == width
__global__ void agg_wide_kernel(const float* __restrict__ in, const float* __restrict__ dinv,
                                const int* __restrict__ rowp, const int* __restrict__ cnt,
                                const int* __restrict__ csrc, const float* __restrict__ cw,
                                const float* __restrict__ bias, float* __restrict__ out,
                                int w, int doBias, int doRelu) {
    int n = blockIdx.x;
    int f = threadIdx.x;
    float dv = dinv[n];
    float acc = dv * dv * in[(size_t)n * w + f];
    int s0 = rowp[n];
    int c = cnt[n];
    for (int j = 0; j < c; j++) {
        int s = csrc[s0 + j];
        float wg = cw[s0 + j];
        acc += wg * in[(size_t)s * w + f];
    }
    if (doBias) acc += bias[f];
    if (doRelu) acc = fmaxf(acc, 0.f);
    out[(size_t)n * w + f] = acc;
}

// width-1 aggregation: one thread per node
__global__ void agg1_kernel(const float* __restrict__ in, const float* __restrict__ dinv,
                            const int* __restrict__ rowp, const int* __restrict__ cnt,
                            const int* __restrict__ csrc, const float* __restrict__ cw,
                            const float* __restrict__ bias, float* __restrict__ out,
                            int n_nodes, int doBias, int doRelu) {
    int n = blockIdx.x * blockDim.x + threadIdx.x;
    if (n >= n_nodes) return;
    float dv = dinv[n];
    float acc = dv * dv * in[n];
    int s0 = rowp[n];
    int c = cnt[n];
    for (int j = 0; j < c; j++) acc += cw[s0 + j] * in[csrc[s0 + j]];
    if (doBias) acc += bias[0];
    if (doRelu) acc = fmaxf(acc, 0.f);
    out[n] = acc;
}

// ---------------- host launcher ----------------

extern "C" void kernel_launch(void* const* d_in, const int* in_sizes, int n_in,
                              void* d_out, int out_size, void* d_ws, size_t ws_size,
                              hipStream_t stream) {
    const float* x = (const float*)d_in[0];
    const int* ei = (const int*)d_in[1];
    const int Nn = in_sizes[0] / 128;      // 50000
    const int E = in_sizes[1] / 2;         // 800000
    const int* src = ei;
    const int* dst = ei + E;

    // workspace layout
    char* ws = (char*)d_ws;
    size_t off = 0;
    auto alloc = [&](size_t bytes) -> char* {
        char* p = ws + off;
        off = (off + bytes + 255) & ~(size_t)255;
        return p;
    };
    int* cnt = (int*)alloc((size_t)Nn * 4);
    int* fill = (int*)alloc((size_t)Nn * 4);
    int* rowp = (int*)alloc((size_t)Nn * 4);
    int* bsums = (int*)alloc(1024);
    float* dinv = (float*)alloc((size_t)Nn * 4);
    int* csrc = (int*)alloc((size_t)E * 4);
    float* cw = (float*)alloc((size_t)E * 4);
    float* bufA = (float*)alloc((size_t)Nn * 256 * 4);
    float* bufB = (float*)alloc((size_t)Nn * 256 * 4);
    (void)ws_size;

    int nbN = (Nn + TPB - 1) / TPB;       // 196
    int nbE = (E + TPB - 1) / TPB;

    // ---- graph prep ----
    zero_int_kernel<<<nbN, TPB, 0, stream>>>(cnt, Nn);
    zero_int_kernel<<<nbN, TPB, 0, stream>>>(fill, Nn);
    count_kernel<<<nbE, TPB, 0, stream>>>(dst, cnt, E);
    dinv_kernel<<<nbN, TPB, 0, stream>>>(cnt, dinv, Nn);
    scan1_kernel<<<nbN, TPB, 0, stream>>>(cnt, rowp, bsums, Nn);
    scan2_kernel<<<1, TPB, 0, stream>>>(bsums, nbN);
    scan3_kernel<<<nbN, TPB, 0, stream>>>(rowp, bsums, Nn);
    fill_kernel<<<nbE, TPB, 0, stream>>>(src, dst, dinv, rowp, fill, csrc, cw, E);

    // ---- layers ----
    struct L { int din, dout; int relu; int aggFirst; };
    const L layers[9] = {
        {128, 128, 1, 0},
        {128, 192, 1, 1},
        {192, 256, 1, 1},
        {256, 256, 1, 0},
        {256, 256, 0, 0},
        {256, 256, 1, 0},
        {256, 192, 1, 0},
        {192, 128, 1, 0},
        {128,   1, 0, 0},
    };

    const float* cur = x;
    for (int i = 0; i < 9; i++) {
        const float* W = (const float*)d_in[2 + 2 * i];
        const float* b = (const float*)d_in[3 + 2 * i];
        const L& L_ = layers[i];
        if (L_.aggFirst) {
            // t = Â cur (width din), then h = t@W + b (relu)
            agg_wide_kernel<<<Nn, L_.din, 0, stream>>>(cur, dinv, rowp, cnt, csrc, cw,
                                                       b, bufA, L_.din, 0, 0);
            dim3 grid(L_.dout / 64, (Nn + 63) / 64);
            gemm_kernel<<<grid, 256, 0, stream>>>(bufA, W, b, bufB, Nn, L_.din, L_.dout,
                                                  1, L_.relu);
            cur = bufB;
        } else {
            // t = cur@W (no bias), then h = Â t + b (relu)
            if (L_.dout == 1) {
                gemv128_kernel<<<(Nn + 3) / 4, 256, 0, stream>>>(cur, W, bufA, Nn);
                agg1_kernel<<<nbN, TPB, 0, stream>>>(bufA, dinv, rowp, cnt, csrc, cw,
                                                     b, (float*)d_out, Nn, 1, L_.relu);
            } else {
                dim3 grid(L_.dout / 64, (Nn + 63) / 64);
                gemm_kernel<<<grid, 256, 0, stream>>>(cur, W, b, bufA, Nn, L_.din, L_.dout,
                                                      0, 0);
                agg_wide_kernel<<<Nn, L_.dout, 0, stream>>>(bufA, dinv, rowp, cnt, csrc, cw,
                                                            b, bufB, L_.dout, 1, L_.relu);
                cur = bufB;
            }
        }
    }
}

// Round 2
// 1592.499 us; speedup vs baseline: 1.2896x; 1.2896x over previous
//
#include <hip/hip_runtime.h>

// ---------------------------------------------------------------------------
// GCN stack: 9 layers of  h = relu( Â (h W) + b ),  Â = D^-1/2 (A+I) D^-1/2
//   * Â(HW) == (ÂH)W  -> aggregate at width min(din,dout) per layer
//   * Â identical across layers -> CSR built once per launch
// R2: wave-per-node float4 gather aggregation (shfl-broadcast indices,
//     4x unrolled independent loads) + 128x128/8x8 fp32 GEMM.
// ---------------------------------------------------------------------------

#define TPB 256

// ---------------- graph prep kernels ----------------

__global__ void zero_int_kernel(int* p, int n) {
    int i = blockIdx.x * blockDim.x + threadIdx.x;
    if (i < n) p[i] = 0;
}

__global__ void count_kernel(const int* __restrict__ dst, int* __restrict__ cnt, int E) {
    int e = blockIdx.x * blockDim.x + threadIdx.x;
    if (e < E) atomicAdd(&cnt[dst[e]], 1);
}

__global__ void dinv_kernel(const int* __restrict__ cnt, float* __restrict__ dinv, int n) {
    int i = blockIdx.x * blockDim.x + threadIdx.x;
    if (i < n) dinv[i] = rsqrtf((float)(cnt[i] + 1));   // +1 self loop, deg>=1
}

__global__ void scan1_kernel(const int* __restrict__ cnt, int* __restrict__ rowp,
                             int* __restrict__ bsums, int n) {
    __shared__ int sh[TPB];
    int t = threadIdx.x;
    int i = blockIdx.x * TPB + t;
    int v = (i < n) ? cnt[i] : 0;
    sh[t] = v;
    __syncthreads();
    for (int off = 1; off < TPB; off <<= 1) {
        int x = (t >= off) ? sh[t - off] : 0;
        __syncthreads();
        sh[t] += x;
        __syncthreads();
    }
    if (i < n) rowp[i] = sh[t] - v;          // exclusive
    if (t == TPB - 1) bsums[blockIdx.x] = sh[t];
}

__global__ void scan2_kernel(int* __restrict__ bsums, int nb) {
    __shared__ int sh[TPB];
    int t = threadIdx.x;
    int v = (t < nb) ? bsums[t] : 0;
    sh[t] = v;
    __syncthreads();
    for (int off = 1; off < TPB; off <<= 1) {
        int x = (t >= off) ? sh[t - off] : 0;
        __syncthreads();
        sh[t] += x;
        __syncthreads();
    }
    if (t < nb) bsums[t] = sh[t] - v;        // exclusive block offsets
}

__global__ void scan3_kernel(int* __restrict__ rowp, const int* __restrict__ bsums, int n) {
    int i = blockIdx.x * TPB + threadIdx.x;
    if (i < n) rowp[i] += bsums[blockIdx.x];
}

__global__ void fill_kernel(const int* __restrict__ src, const int* __restrict__ dst,
                            const float* __restrict__ dinv,
                            const int* __restrict__ rowp, int* __restrict__ fill,
                            int* __restrict__ csrc, float* __restrict__ cw, int E) {
    int e = blockIdx.x * blockDim.x + threadIdx.x;
    if (e >= E) return;
    int s = src[e], d = dst[e];
    int pos = rowp[d] + atomicAdd(&fill[d], 1);
    csrc[pos] = s;
    cw[pos] = dinv[s] * dinv[d];
}

// ---------------- dense kernels ----------------

// C[M,Nc] = A[M,K] @ B[K,Nc] (+bias,relu). 128x128 tile, 8x8 per thread.
// K % 16 == 0. Nc % 4 == 0 (guards handle Nc not multiple of 128, M tail).
__global__ __launch_bounds__(256) void gemm128_kernel(
    const float* __restrict__ A, const float* __restrict__ B,
    const float* __restrict__ bias, float* __restrict__ C,
    int M, int K, int Nc, int doBias, int doRelu) {
    __shared__ float As[16][132];
    __shared__ float Bs[16][132];
    int t = threadIdx.x;
    int tx = t & 15;            // col group (8 cols each)
    int ty = t >> 4;            // row group (8 rows each)
    int row0 = blockIdx.y * 128;
    int col0 = blockIdx.x * 128;

    float acc[8][8];
#pragma unroll
    for (int i = 0; i < 8; i++)
#pragma unroll
        for (int j = 0; j < 8; j++) acc[i][j] = 0.f;

    int aRow = t >> 2;          // 0..63 (plus +64 on second half)
    int aCol = (t & 3) * 4;     // 0,4,8,12

    for (int k0 = 0; k0 < K; k0 += 16) {
        // A tile: 128x16, stored transposed As[k][m]
#pragma unroll
        for (int h = 0; h < 2; ++h) {
            int r = aRow + h * 64;
            int gr = row0 + r;
            float4 av = make_float4(0.f, 0.f, 0.f, 0.f);
            if (gr < M) av = *(const float4*)(A + (size_t)gr * K + k0 + aCol);
            As[aCol + 0][r] = av.x;
            As[aCol + 1][r] = av.y;
            As[aCol + 2][r] = av.z;
            As[aCol + 3][r] = av.w;
        }
        // B tile: 16x128
#pragma unroll
        for (int h = 0; h < 2; ++h) {
            int id = t + h * 256;
            int br = id >> 5;
            int bc = (id & 31) * 4;
            int gc = col0 + bc;
            float4 bv = make_float4(0.f, 0.f, 0.f, 0.f);
            if (gc < Nc) bv = *(const float4*)(B + (size_t)(k0 + br) * Nc + gc);
            *(float4*)&Bs[br][bc] = bv;
        }
        __syncthreads();
#pragma unroll
        for (int kk = 0; kk < 16; kk++) {
            float a[8], b[8];
#pragma unroll
            for (int i = 0; i < 8; i++) a[i] = As[kk][ty * 8 + i];
#pragma unroll
            for (int j = 0; j < 8; j++) b[j] = Bs[kk][tx * 8 + j];
#pragma unroll
            for (int i = 0; i < 8; i++)
#pragma unroll
                for (int j = 0; j < 8; j++) acc[i][j] += a[i] * b[j];
        }
        __syncthreads();
    }

#pragma unroll
    for (int i = 0; i < 8; i++) {
        int gr = row0 + ty * 8 + i;
        if (gr >= M) continue;
#pragma unroll
        for (int jj = 0; jj < 2; jj++) {
            int gc = col0 + tx * 8 + jj * 4;
            if (gc >= Nc) continue;
            float4 v;
            float* pv = &v.x;
#pragma unroll
            for (int q = 0; q < 4; q++) {
                float x = acc[i][jj * 4 + q];
                if (doBias) x += bias[gc + q];
                if (doRelu) x = fmaxf(x, 0.f);
                pv[q] = x;
            }
            *(float4*)(C + (size_t)gr * Nc + gc) = v;
        }
    }
}

// out[m] = dot(A[m,0:128], w[0:128])   (one wave per row)
__global__ void gemv128_kernel(const float* __restrict__ A, const float* __restrict__ w,
                               float* __restrict__ out, int M) {
    int wid = (blockIdx.x * blockDim.x + threadIdx.x) >> 6;
    int lane = threadIdx.x & 63;
    if (wid >= M) return;
    const float* a = A + (size_t)wid * 128;
    float s = a[lane] * w[lane] + a[lane + 64] * w[lane + 64];
#pragma unroll
    for (int off = 32; off > 0; off >>= 1) s += __shfl_down(s, off);
    if (lane == 0) out[wid] = s;
}

// ---------------- aggregation kernels ----------------

// One WAVE per node. Lane holds float4 [lane*4, lane*4+4) of the row.
// Neighbor (idx,weight) preloaded into lane registers, broadcast via shfl.
// 4x unrolled: 4 independent row-gathers in flight per wave.
__global__ __launch_bounds__(256) void agg_vec_kernel(
    const float* __restrict__ in, const float* __restrict__ dinv,
    const int* __restrict__ rowp, const int* __restrict__ cnt,
    const int* __restrict__ csrc, const float* __restrict__ cw,
    const float* __restrict__ bias, float* __restrict__ out,
    int w, int n_nodes, int doBias, int doRelu) {
    int node = blockIdx.x * 4 + (threadIdx.x >> 6);
    if (node >= n_nodes) return;
    int lane = threadIdx.x & 63;
    int nvec = w >> 2;                      // 32 / 48 / 64
    bool act = lane < nvec;
    const float4* in4 = (const float4*)in;

    float4 a0 = make_float4(0.f, 0.f, 0.f, 0.f);
    float4 a1 = a0, a2 = a0, a3 = a0;

    float dv = dinv[node];
    if (act) {
        float4 v = in4[(size_t)node * nvec + lane];
        float sw = dv * dv;
        a0.x = sw * v.x; a0.y = sw * v.y; a0.z = sw * v.z; a0.w = sw * v.w;
    }

    int s0 = rowp[node];
    int c = cnt[node];
    for (int base = 0; base < c; base += 64) {
        int m = c - base; if (m > 64) m = 64;
        int sj = 0; float wj = 0.f;
        if (lane < m) { sj = csrc[s0 + base + lane]; wj = cw[s0 + base + lane]; }
        int j = 0;
        for (; j + 4 <= m; j += 4) {
            int i0 = __shfl(sj, j),     i1 = __shfl(sj, j + 1);
            int i2 = __shfl(sj, j + 2), i3 = __shfl(sj, j + 3);
            float w0 = __shfl(wj, j),     w1 = __shfl(wj, j + 1);
            float w2 = __shfl(wj, j + 2), w3 = __shfl(wj, j + 3);
            if (act) {
                float4 v0 = in4[(size_t)i0 * nvec + lane];
                float4 v1 = in4[(size_t)i1 * nvec + lane];
                float4 v2 = in4[(size_t)i2 * nvec + lane];
                float4 v3 = in4[(size_t)i3 * nvec + lane];
                a0.x += w0 * v0.x; a0.y += w0 * v0.y; a0.z += w0 * v0.z; a0.w += w0 * v0.w;
                a1.x += w1 * v1.x; a1.y += w1 * v1.y; a1.z += w1 * v1.z; a1.w += w1 * v1.w;
                a2.x += w2 * v2.x; a2.y += w2 * v2.y; a2.z += w2 * v2.z; a2.w += w2 * v2.w;
                a3.x += w3 * v3.x; a3.y += w3 * v3.y; a3.z += w3 * v3.z; a3.w += w3 * v3.w;
            }
        }
        for (; j < m; ++j) {
            int s = __shfl(sj, j);
            float ww = __shfl(wj, j);
            if (act) {
                float4 v = in4[(size_t)s * nvec + lane];
                a0.x += ww * v.x; a0.y += ww * v.y; a0.z += ww * v.z; a0.w += ww * v.w;
            }
        }
    }

    a0.x = (a0.x + a1.x) + (a2.x + a3.x);
    a0.y = (a0.y + a1.y) + (a2.y + a3.y);
    a0.z = (a0.z + a1.z) + (a2.z + a3.z);
    a0.w = (a0.w + a1.w) + (a2.w + a3.w);

    if (act) {
        if (doBias) {
            float4 bb = ((const float4*)bias)[lane];
            a0.x += bb.x; a0.y += bb.y; a0.z += bb.z; a0.w += bb.w;
        }
        if (doRelu) {
            a0.x = fmaxf(a0.x, 0.f); a0.y = fmaxf(a0.y, 0.f);
            a0.z = fmaxf(a0.z, 0.f); a0.w = fmaxf(a0.w, 0.f);
        }
        ((float4*)out)[(size_t)node * nvec + lane] = a0;
    }
}

// width-1 aggregation: one thread per node
__global__ void agg1_kernel(const float* __restrict__ in, const float* __restrict__ dinv,
                            const int* __restrict__ rowp, const int* __restrict__ cnt,
                            const int* __restrict__ csrc, const float* __restrict__ cw,
                            const float* __restrict__ bias, float* __restrict__ out,
                            int n_nodes, int doBias, int doRelu) {
    int n = blockIdx.x * blockDim.x + threadIdx.x;
    if (n >= n_nodes) return;
    float dv = dinv[n];
    float acc = dv * dv * in[n];
    int s0 = rowp[n];
    int c = cnt[n];
    for (int j = 0; j < c; j++) acc += cw[s0 + j] * in[csrc[s0 + j]];
    if (doBias) acc += bias[0];
    if (doRelu) acc = fmaxf(acc, 0.f);
    out[n] = acc;
}

// ---------------- host launcher ----------------

extern "C" void kernel_launch(void* const* d_in, const int* in_sizes, int n_in,
                              void* d_out, int out_size, void* d_ws, size_t ws_size,
                              hipStream_t stream) {
    const float* x = (const float*)d_in[0];
    const int* ei = (const int*)d_in[1];
    const int Nn = in_sizes[0] / 128;      // 50000
    const int E = in_sizes[1] / 2;         // 800000
    const int* src = ei;
    const int* dst = ei + E;

    char* ws = (char*)d_ws;
    size_t off = 0;
    auto alloc = [&](size_t bytes) -> char* {
        char* p = ws + off;
        off = (off + bytes + 255) & ~(size_t)255;
        return p;
    };
    int* cnt = (int*)alloc((size_t)Nn * 4);
    int* fill = (int*)alloc((size_t)Nn * 4);
    int* rowp = (int*)alloc((size_t)Nn * 4);
    int* bsums = (int*)alloc(1024);
    float* dinv = (float*)alloc((size_t)Nn * 4);
    int* csrc = (int*)alloc((size_t)E * 4);
    float* cw = (float*)alloc((size_t)E * 4);
    float* bufA = (float*)alloc((size_t)Nn * 256 * 4);
    float* bufB = (float*)alloc((size_t)Nn * 256 * 4);
    (void)ws_size;

    int nbN = (Nn + TPB - 1) / TPB;
    int nbE = (E + TPB - 1) / TPB;

    // ---- graph prep ----
    zero_int_kernel<<<nbN, TPB, 0, stream>>>(cnt, Nn);
    zero_int_kernel<<<nbN, TPB, 0, stream>>>(fill, Nn);
    count_kernel<<<nbE, TPB, 0, stream>>>(dst, cnt, E);
    dinv_kernel<<<nbN, TPB, 0, stream>>>(cnt, dinv, Nn);
    scan1_kernel<<<nbN, TPB, 0, stream>>>(cnt, rowp, bsums, Nn);
    scan2_kernel<<<1, TPB, 0, stream>>>(bsums, nbN);
    scan3_kernel<<<nbN, TPB, 0, stream>>>(rowp, bsums, Nn);
    fill_kernel<<<nbE, TPB, 0, stream>>>(src, dst, dinv, rowp, fill, csrc, cw, E);

    // ---- layers ----
    struct L { int din, dout; int relu; int aggFirst; };
    const L layers[9] = {
        {128, 128, 1, 0},
        {128, 192, 1, 1},
        {192, 256, 1, 1},
        {256, 256, 1, 0},
        {256, 256, 0, 0},
        {256, 256, 1, 0},
        {256, 192, 1, 0},
        {192, 128, 1, 0},
        {128,   1, 0, 0},
    };

    int aggBlocks = (Nn + 3) / 4;          // one wave per node

    const float* cur = x;
    for (int i = 0; i < 9; i++) {
        const float* W = (const float*)d_in[2 + 2 * i];
        const float* b = (const float*)d_in[3 + 2 * i];
        const L& L_ = layers[i];
        if (L_.aggFirst) {
            // t = Â cur (width din), then h = t@W + b (relu)
            agg_vec_kernel<<<aggBlocks, 256, 0, stream>>>(cur, dinv, rowp, cnt, csrc, cw,
                                                          b, bufA, L_.din, Nn, 0, 0);
            dim3 grid((L_.dout + 127) / 128, (Nn + 127) / 128);
            gemm128_kernel<<<grid, 256, 0, stream>>>(bufA, W, b, bufB, Nn, L_.din, L_.dout,
                                                     1, L_.relu);
            cur = bufB;
        } else {
            // t = cur@W (no bias), then h = Â t + b (relu)
            if (L_.dout == 1) {
                gemv128_kernel<<<(Nn + 3) / 4, 256, 0, stream>>>(cur, W, bufA, Nn);
                agg1_kernel<<<nbN, TPB, 0, stream>>>(bufA, dinv, rowp, cnt, csrc, cw,
                                                     b, (float*)d_out, Nn, 1, L_.relu);
            } else {
                dim3 grid((L_.dout + 127) / 128, (Nn + 127) / 128);
                gemm128_kernel<<<grid, 256, 0, stream>>>(cur, W, b, bufA, Nn, L_.din, L_.dout,
                                                         0, 0);
                agg_vec_kernel<<<aggBlocks, 256, 0, stream>>>(bufA, dinv, rowp, cnt, csrc, cw,
                                                              b, bufB, L_.dout, Nn, 1, L_.relu);
                cur = bufB;
            }
        }
    }
}

// Round 3
// 1354.321 us; speedup vs baseline: 1.5164x; 1.1759x over previous
//
#include <hip/hip_runtime.h>

// ---------------------------------------------------------------------------
// GCN stack: 9 layers of  h = relu( Â (h W) + b ),  Â = D^-1/2 (A+I) D^-1/2
//   * Â(HW) == (ÂH)W  -> aggregate at width min(din,dout) per layer
//   * Â identical across layers -> CSR (with self-loops folded in) built once
// R3: bf16 gather rows (fp32 accumulate) to halve agg memory traffic;
//     uniform packed-edge loads (no shfl); 2-group waves for width-128;
//     conflict-free strided-microtile fp32 GEMM with K-tile reg prefetch.
// ---------------------------------------------------------------------------

#define TPB 256

__device__ __forceinline__ unsigned bf16rne(float x) {
    unsigned u = __float_as_uint(x);
    return (u + 0x7fffu + ((u >> 16) & 1u)) >> 16;
}

// ---------------- graph prep kernels ----------------

__global__ void zero_int_kernel(int* p, int n) {
    int i = blockIdx.x * blockDim.x + threadIdx.x;
    if (i < n) p[i] = 0;
}

__global__ void count_kernel(const int* __restrict__ dst, int* __restrict__ cnt, int E) {
    int e = blockIdx.x * blockDim.x + threadIdx.x;
    if (e < E) atomicAdd(&cnt[dst[e]], 1);
}

__global__ void dinv_kernel(const int* __restrict__ cnt, float* __restrict__ dinv, int n) {
    int i = blockIdx.x * blockDim.x + threadIdx.x;
    if (i < n) dinv[i] = rsqrtf((float)(cnt[i] + 1));   // +1 self loop
}

// scan over degree = cnt+1 (self loop included in CSR)
__global__ void scan1_kernel(const int* __restrict__ cnt, int* __restrict__ rowp,
                             int* __restrict__ bsums, int n) {
    __shared__ int sh[TPB];
    int t = threadIdx.x;
    int i = blockIdx.x * TPB + t;
    int v = (i < n) ? (cnt[i] + 1) : 0;
    sh[t] = v;
    __syncthreads();
    for (int off = 1; off < TPB; off <<= 1) {
        int x = (t >= off) ? sh[t - off] : 0;
        __syncthreads();
        sh[t] += x;
        __syncthreads();
    }
    if (i < n) rowp[i] = sh[t] - v;          // exclusive
    if (t == TPB - 1) bsums[blockIdx.x] = sh[t];
}

__global__ void scan2_kernel(int* __restrict__ bsums, int nb) {
    __shared__ int sh[TPB];
    int t = threadIdx.x;
    int v = (t < nb) ? bsums[t] : 0;
    sh[t] = v;
    __syncthreads();
    for (int off = 1; off < TPB; off <<= 1) {
        int x = (t >= off) ? sh[t - off] : 0;
        __syncthreads();
        sh[t] += x;
        __syncthreads();
    }
    if (t < nb) bsums[t] = sh[t] - v;
}

__global__ void scan3_kernel(int* __restrict__ rowp, const int* __restrict__ bsums, int n) {
    int i = blockIdx.x * TPB + threadIdx.x;
    if (i < n) rowp[i] += bsums[blockIdx.x];
}

// real edges -> slots [rowp[d], rowp[d]+cnt[d])
__global__ void fill_kernel(const int* __restrict__ src, const int* __restrict__ dst,
                            const float* __restrict__ dinv,
                            const int* __restrict__ rowp, int* __restrict__ fill,
                            uint2* __restrict__ edges, int E) {
    int e = blockIdx.x * blockDim.x + threadIdx.x;
    if (e >= E) return;
    int s = src[e], d = dst[e];
    int pos = rowp[d] + atomicAdd(&fill[d], 1);
    edges[pos] = make_uint2((unsigned)s, __float_as_uint(dinv[s] * dinv[d]));
}

// self edge in last slot
__global__ void self_kernel(const int* __restrict__ cnt, const int* __restrict__ rowp,
                            const float* __restrict__ dinv, uint2* __restrict__ edges, int n) {
    int i = blockIdx.x * blockDim.x + threadIdx.x;
    if (i >= n) return;
    float dv = dinv[i];
    edges[rowp[i] + cnt[i]] = make_uint2((unsigned)i, __float_as_uint(dv * dv));
}

// ---------------- dense GEMM ----------------

// C[M,Nc] = A[M,K] @ B[K,Nc] (+bias,relu). 128x128 tile, strided 8x8 microtile
// (conflict-free LDS reads). fp32 A/B; output fp32 or bf16. K%16==0.
__global__ __launch_bounds__(256) void gemm128_kernel(
    const float* __restrict__ A, const float* __restrict__ B,
    const float* __restrict__ bias, void* __restrict__ C,
    int M, int K, int Nc, int doBias, int doRelu, int outBf16) {
    __shared__ float As[16][132];
    __shared__ float Bs[16][132];
    int t = threadIdx.x;
    int tx = t & 15;            // col lane: cols tx + 16*j
    int ty = t >> 4;            // row lane: rows ty + 16*i
    int row0 = blockIdx.y * 128;
    int col0 = blockIdx.x * 128;

    int aRow = t >> 2;          // 0..63 (+64)
    int aCol = (t & 3) * 4;     // 0,4,8,12

    float acc[8][8];
#pragma unroll
    for (int i = 0; i < 8; i++)
#pragma unroll
        for (int j = 0; j < 8; j++) acc[i][j] = 0.f;

    float4 pa[2], pb[2];
    auto loadT = [&](int k0) {
#pragma unroll
        for (int h = 0; h < 2; ++h) {
            int gr = row0 + aRow + h * 64;
            pa[h] = make_float4(0.f, 0.f, 0.f, 0.f);
            if (gr < M) pa[h] = *(const float4*)(A + (size_t)gr * K + k0 + aCol);
            int id = t + h * 256;
            int br = id >> 5;
            int bc = (id & 31) * 4;
            pb[h] = make_float4(0.f, 0.f, 0.f, 0.f);
            if (col0 + bc < Nc) pb[h] = *(const float4*)(B + (size_t)(k0 + br) * Nc + col0 + bc);
        }
    };

    loadT(0);
    for (int k0 = 0; k0 < K; k0 += 16) {
#pragma unroll
        for (int h = 0; h < 2; ++h) {
            int r = aRow + h * 64;
            As[aCol + 0][r] = pa[h].x;
            As[aCol + 1][r] = pa[h].y;
            As[aCol + 2][r] = pa[h].z;
            As[aCol + 3][r] = pa[h].w;
            int id = t + h * 256;
            *(float4*)&Bs[id >> 5][(id & 31) * 4] = pb[h];
        }
        __syncthreads();
        if (k0 + 16 < K) loadT(k0 + 16);    // prefetch overlaps compute
#pragma unroll
        for (int kk = 0; kk < 16; kk++) {
            float a[8], b[8];
#pragma unroll
            for (int i = 0; i < 8; i++) a[i] = As[kk][ty + 16 * i];
#pragma unroll
            for (int j = 0; j < 8; j++) b[j] = Bs[kk][tx + 16 * j];
#pragma unroll
            for (int i = 0; i < 8; i++)
#pragma unroll
                for (int j = 0; j < 8; j++) acc[i][j] += a[i] * b[j];
        }
        __syncthreads();
    }

#pragma unroll
    for (int i = 0; i < 8; i++) {
        int gr = row0 + ty + 16 * i;
        if (gr >= M) continue;
#pragma unroll
        for (int j = 0; j < 8; j++) {
            int gc = col0 + tx + 16 * j;
            if (gc >= Nc) continue;
            float x = acc[i][j];
            if (doBias) x += bias[gc];
            if (doRelu) x = fmaxf(x, 0.f);
            if (outBf16) ((unsigned short*)C)[(size_t)gr * Nc + gc] = (unsigned short)bf16rne(x);
            else ((float*)C)[(size_t)gr * Nc + gc] = x;
        }
    }
}

// out[m] = dot(A[m,0:128], w[0:128])   (one wave per row, fp32 in)
__global__ void gemv128_kernel(const float* __restrict__ A, const float* __restrict__ w,
                               float* __restrict__ out, int M) {
    int wid = (blockIdx.x * blockDim.x + threadIdx.x) >> 6;
    int lane = threadIdx.x & 63;
    if (wid >= M) return;
    const float* a = A + (size_t)wid * 128;
    float s = a[lane] * w[lane] + a[lane + 64] * w[lane + 64];
#pragma unroll
    for (int off = 32; off > 0; off >>= 1) s += __shfl_down(s, off);
    if (lane == 0) out[wid] = s;
}

// ---------------- aggregation ----------------

// One WAVE per node, bf16 input rows, fp32 accumulate.
// Lane fl holds features [4*fl, 4*fl+4) as one uint2 (4 bf16).
// nvec = w/4 (32/48/64). nvec==32: two edge-groups per wave (all lanes busy).
// Edge (src,weight) packed uint2, loaded wave-uniformly (HW broadcast).
__global__ __launch_bounds__(256) void agg_bf16_kernel(
    const unsigned* __restrict__ in /*bf16 pairs*/, const int* __restrict__ rowp,
    const int* __restrict__ cnt, const uint2* __restrict__ edges,
    const float* __restrict__ bias, void* __restrict__ out,
    int nvec, int n_nodes, int doBias, int doRelu, int outBf16) {
    int node = blockIdx.x * 4 + (threadIdx.x >> 6);
    if (node >= n_nodes) return;
    int lane = threadIdx.x & 63;
    int G, g, fl;
    if (nvec == 32) { G = 2; g = lane >> 5; fl = lane & 31; }
    else            { G = 1; g = 0; fl = lane; if (lane >= nvec) return; }

    const uint2* in2 = (const uint2*)in;
    float4 a0 = make_float4(0.f, 0.f, 0.f, 0.f);
    float4 a1 = a0, a2 = a0, a3 = a0;

    int c = cnt[node] + 1;                  // + self edge
    int s0 = rowp[node];

    int j = g;
    for (; j + 3 * G < c; j += 4 * G) {
        uint2 e0 = edges[s0 + j];
        uint2 e1 = edges[s0 + j + G];
        uint2 e2 = edges[s0 + j + 2 * G];
        uint2 e3 = edges[s0 + j + 3 * G];
        uint2 p0 = in2[(size_t)e0.x * nvec + fl];
        uint2 p1 = in2[(size_t)e1.x * nvec + fl];
        uint2 p2 = in2[(size_t)e2.x * nvec + fl];
        uint2 p3 = in2[(size_t)e3.x * nvec + fl];
        float w0 = __uint_as_float(e0.y), w1 = __uint_as_float(e1.y);
        float w2 = __uint_as_float(e2.y), w3 = __uint_as_float(e3.y);
        a0.x += w0 * __uint_as_float(p0.x << 16);
        a0.y += w0 * __uint_as_float(p0.x & 0xffff0000u);
        a0.z += w0 * __uint_as_float(p0.y << 16);
        a0.w += w0 * __uint_as_float(p0.y & 0xffff0000u);
        a1.x += w1 * __uint_as_float(p1.x << 16);
        a1.y += w1 * __uint_as_float(p1.x & 0xffff0000u);
        a1.z += w1 * __uint_as_float(p1.y << 16);
        a1.w += w1 * __uint_as_float(p1.y & 0xffff0000u);
        a2.x += w2 * __uint_as_float(p2.x << 16);
        a2.y += w2 * __uint_as_float(p2.x & 0xffff0000u);
        a2.z += w2 * __uint_as_float(p2.y << 16);
        a2.w += w2 * __uint_as_float(p2.y & 0xffff0000u);
        a3.x += w3 * __uint_as_float(p3.x << 16);
        a3.y += w3 * __uint_as_float(p3.x & 0xffff0000u);
        a3.z += w3 * __uint_as_float(p3.y << 16);
        a3.w += w3 * __uint_as_float(p3.y & 0xffff0000u);
    }
    for (; j < c; j += G) {
        uint2 e = edges[s0 + j];
        uint2 p = in2[(size_t)e.x * nvec + fl];
        float w = __uint_as_float(e.y);
        a0.x += w * __uint_as_float(p.x << 16);
        a0.y += w * __uint_as_float(p.x & 0xffff0000u);
        a0.z += w * __uint_as_float(p.y << 16);
        a0.w += w * __uint_as_float(p.y & 0xffff0000u);
    }

    a0.x = (a0.x + a1.x) + (a2.x + a3.x);
    a0.y = (a0.y + a1.y) + (a2.y + a3.y);
    a0.z = (a0.z + a1.z) + (a2.z + a3.z);
    a0.w = (a0.w + a1.w) + (a2.w + a3.w);

    if (nvec == 32) {                       // combine the two edge-groups
        a0.x += __shfl_down(a0.x, 32);
        a0.y += __shfl_down(a0.y, 32);
        a0.z += __shfl_down(a0.z, 32);
        a0.w += __shfl_down(a0.w, 32);
        if (lane >= 32) return;
    }

    if (doBias) {
        float4 bb = ((const float4*)bias)[fl];
        a0.x += bb.x; a0.y += bb.y; a0.z += bb.z; a0.w += bb.w;
    }
    if (doRelu) {
        a0.x = fmaxf(a0.x, 0.f); a0.y = fmaxf(a0.y, 0.f);
        a0.z = fmaxf(a0.z, 0.f); a0.w = fmaxf(a0.w, 0.f);
    }
    if (outBf16) {
        uint2 o;
        o.x = bf16rne(a0.x) | (bf16rne(a0.y) << 16);
        o.y = bf16rne(a0.z) | (bf16rne(a0.w) << 16);
        ((uint2*)out)[(size_t)node * nvec + fl] = o;
    } else {
        ((float4*)out)[(size_t)node * nvec + fl] = a0;
    }
}

// width-1 aggregation, fp32 in/out: one thread per node
__global__ void agg1_kernel(const float* __restrict__ in, const int* __restrict__ rowp,
                            const int* __restrict__ cnt, const uint2* __restrict__ edges,
                            const float* __restrict__ bias, float* __restrict__ out,
                            int n_nodes, int doRelu) {
    int n = blockIdx.x * blockDim.x + threadIdx.x;
    if (n >= n_nodes) return;
    float acc = 0.f;
    int s0 = rowp[n];
    int c = cnt[n] + 1;
    for (int j = 0; j < c; j++) {
        uint2 e = edges[s0 + j];
        acc += __uint_as_float(e.y) * in[e.x];
    }
    acc += bias[0];
    if (doRelu) acc = fmaxf(acc, 0.f);
    out[n] = acc;
}

// ---------------- host launcher ----------------

extern "C" void kernel_launch(void* const* d_in, const int* in_sizes, int n_in,
                              void* d_out, int out_size, void* d_ws, size_t ws_size,
                              hipStream_t stream) {
    const float* x = (const float*)d_in[0];
    const int* ei = (const int*)d_in[1];
    const int Nn = in_sizes[0] / 128;      // 50000
    const int E = in_sizes[1] / 2;         // 800000
    const int* src = ei;
    const int* dst = ei + E;

    char* ws = (char*)d_ws;
    size_t off = 0;
    auto alloc = [&](size_t bytes) -> char* {
        char* p = ws + off;
        off = (off + bytes + 255) & ~(size_t)255;
        return p;
    };
    int* cnt = (int*)alloc((size_t)Nn * 4);
    int* fill = (int*)alloc((size_t)Nn * 4);
    int* rowp = (int*)alloc((size_t)Nn * 4);
    int* bsums = (int*)alloc(1024);
    float* dinv = (float*)alloc((size_t)Nn * 4);
    uint2* edges = (uint2*)alloc((size_t)(E + Nn) * 8);
    float* F1 = (float*)alloc((size_t)Nn * 256 * 4);
    float* F2 = (float*)alloc((size_t)Nn * 256 * 4);
    unsigned* B1 = (unsigned*)alloc((size_t)Nn * 256 * 2);   // bf16, up to width 256
    unsigned* B2 = (unsigned*)alloc((size_t)Nn * 128 * 2);   // bf16, width 128 only
    (void)ws_size;

    int nbN = (Nn + TPB - 1) / TPB;
    int nbE = (E + TPB - 1) / TPB;

    // ---- graph prep (CSR incl. self loops, packed (src,weight) edges) ----
    zero_int_kernel<<<nbN, TPB, 0, stream>>>(cnt, Nn);
    zero_int_kernel<<<nbN, TPB, 0, stream>>>(fill, Nn);
    count_kernel<<<nbE, TPB, 0, stream>>>(dst, cnt, E);
    dinv_kernel<<<nbN, TPB, 0, stream>>>(cnt, dinv, Nn);
    scan1_kernel<<<nbN, TPB, 0, stream>>>(cnt, rowp, bsums, Nn);
    scan2_kernel<<<1, TPB, 0, stream>>>(bsums, nbN);
    scan3_kernel<<<nbN, TPB, 0, stream>>>(rowp, bsums, Nn);
    fill_kernel<<<nbE, TPB, 0, stream>>>(src, dst, dinv, rowp, fill, edges, E);
    self_kernel<<<nbN, TPB, 0, stream>>>(cnt, rowp, dinv, edges, Nn);

    int aggBlocks = (Nn + 3) / 4;

    auto gemm = [&](const float* A, int i, void* C, int M, int K, int Nc,
                    int doBias, int doRelu, int outBf16) {
        const float* W = (const float*)d_in[2 + 2 * i];
        const float* b = (const float*)d_in[3 + 2 * i];
        dim3 grid((Nc + 127) / 128, (M + 127) / 128);
        gemm128_kernel<<<grid, 256, 0, stream>>>(A, W, b, C, M, K, Nc, doBias, doRelu, outBf16);
    };
    auto agg = [&](const unsigned* in, void* outp, int w, int i, int doBias, int doRelu,
                   int outBf16) {
        const float* b = doBias ? (const float*)d_in[3 + 2 * i] : (const float*)d_in[3];
        agg_bf16_kernel<<<aggBlocks, 256, 0, stream>>>(in, rowp, cnt, edges, b, outp,
                                                       w / 4, Nn, doBias, doRelu, outBf16);
    };

    // L0 (128->128, relu): t0 = x@W0 -> B1(bf16); h1 = Â t0 + b0, relu -> B2(bf16)
    gemm(x, 0, B1, Nn, 128, 128, 0, 0, 1);
    agg(B1, B2, 128, 0, 1, 1, 1);
    // L1 (128->192, relu, aggFirst): u1 = Â h1 -> F1; h2 = u1@W1+b1 relu -> B1(bf16)
    agg(B2, F1, 128, 1, 0, 0, 0);
    gemm(F1, 1, B1, Nn, 128, 192, 1, 1, 1);
    // L2 (192->256, relu, aggFirst): u2 = Â h2 -> F1; h3 = u2@W2+b2 relu -> F2 (fp32)
    agg(B1, F1, 192, 2, 0, 0, 0);
    gemm(F1, 2, F2, Nn, 192, 256, 1, 1, 0);
    // L3 (256->256, relu): t = h3@W3 -> B1; h4 = Â t + b3 relu -> F1
    gemm(F2, 3, B1, Nn, 256, 256, 0, 0, 1);
    agg(B1, F1, 256, 3, 1, 1, 0);
    // L4 (256->256, NO relu): t = h4@W4 -> B1; h5 = Â t + b4 -> F2
    gemm(F1, 4, B1, Nn, 256, 256, 0, 0, 1);
    agg(B1, F2, 256, 4, 1, 0, 0);
    // L5 (256->256, relu): t = h5@W5 -> B1; h6 = Â t + b5 relu -> F1
    gemm(F2, 5, B1, Nn, 256, 256, 0, 0, 1);
    agg(B1, F1, 256, 5, 1, 1, 0);
    // L6 (256->192, relu): t = h6@W6 -> B1; h7 = Â t + b6 relu -> F2
    gemm(F1, 6, B1, Nn, 256, 192, 0, 0, 1);
    agg(B1, F2, 192, 6, 1, 1, 0);
    // L7 (192->128, relu): t = h7@W7 -> B1; h8 = Â t + b7 relu -> F1
    gemm(F2, 7, B1, Nn, 192, 128, 0, 0, 1);
    agg(B1, F1, 128, 7, 1, 1, 0);
    // L8 (128->1, no relu): s = h8@W8 -> F2; out = Â s + b8
    gemv128_kernel<<<(Nn + 3) / 4, 256, 0, stream>>>(F1, (const float*)d_in[2 + 16], F2, Nn);
    agg1_kernel<<<nbN, TPB, 0, stream>>>(F2, rowp, cnt, edges, (const float*)d_in[3 + 16],
                                         (float*)d_out, Nn, 0);
}

// Round 4
// 890.716 us; speedup vs baseline: 2.3057x; 1.5205x over previous
//
#include <hip/hip_runtime.h>

// ---------------------------------------------------------------------------
// GCN stack: 9 layers of  h = relu( Â (h W) + b ),  Â = D^-1/2 (A+I) D^-1/2
//   * Â(HW) == (ÂH)W  -> aggregate at width min(din,dout) per layer
//   * Â identical across layers -> CSR (self-loops folded) built once
// R4: bf16 MFMA GEMM (16x16x32), global_load_lds width-16 staging, bf16
//     transposed weights prepped once. All activations bf16, fp32 accum.
// ---------------------------------------------------------------------------

#define TPB 256

using bf16x8 = __attribute__((ext_vector_type(8))) __bf16;
using f32x4  = __attribute__((ext_vector_type(4))) float;

__device__ __forceinline__ unsigned bf16rne(float x) {
    unsigned u = __float_as_uint(x);
    return (u + 0x7fffu + ((u >> 16) & 1u)) >> 16;
}

// async global->LDS, 16B per lane. l is the WAVE-UNIFORM base; HW adds lane*16.
__device__ __forceinline__ void stage16(const unsigned short* g, unsigned short* l) {
#if __has_builtin(__builtin_amdgcn_global_load_lds)
    __builtin_amdgcn_global_load_lds((const __attribute__((address_space(1))) void*)g,
                                     (__attribute__((address_space(3))) void*)l, 16, 0, 0);
#else
    *(uint4*)((char*)l + (threadIdx.x & 63) * 16) = *(const uint4*)g;
#endif
}

// ---------------- graph prep kernels ----------------

__global__ void zero_int_kernel(int* p, int n) {
    int i = blockIdx.x * blockDim.x + threadIdx.x;
    if (i < n) p[i] = 0;
}

__global__ void count_kernel(const int* __restrict__ dst, int* __restrict__ cnt, int E) {
    int e = blockIdx.x * blockDim.x + threadIdx.x;
    if (e < E) atomicAdd(&cnt[dst[e]], 1);
}

__global__ void dinv_kernel(const int* __restrict__ cnt, float* __restrict__ dinv, int n) {
    int i = blockIdx.x * blockDim.x + threadIdx.x;
    if (i < n) dinv[i] = rsqrtf((float)(cnt[i] + 1));
}

__global__ void scan1_kernel(const int* __restrict__ cnt, int* __restrict__ rowp,
                             int* __restrict__ bsums, int n) {
    __shared__ int sh[TPB];
    int t = threadIdx.x;
    int i = blockIdx.x * TPB + t;
    int v = (i < n) ? (cnt[i] + 1) : 0;       // +1 self loop in CSR
    sh[t] = v;
    __syncthreads();
    for (int off = 1; off < TPB; off <<= 1) {
        int x = (t >= off) ? sh[t - off] : 0;
        __syncthreads();
        sh[t] += x;
        __syncthreads();
    }
    if (i < n) rowp[i] = sh[t] - v;
    if (t == TPB - 1) bsums[blockIdx.x] = sh[t];
}

__global__ void scan2_kernel(int* __restrict__ bsums, int nb) {
    __shared__ int sh[TPB];
    int t = threadIdx.x;
    int v = (t < nb) ? bsums[t] : 0;
    sh[t] = v;
    __syncthreads();
    for (int off = 1; off < TPB; off <<= 1) {
        int x = (t >= off) ? sh[t - off] : 0;
        __syncthreads();
        sh[t] += x;
        __syncthreads();
    }
    if (t < nb) bsums[t] = sh[t] - v;
}

__global__ void scan3_kernel(int* __restrict__ rowp, const int* __restrict__ bsums, int n) {
    int i = blockIdx.x * TPB + threadIdx.x;
    if (i < n) rowp[i] += bsums[blockIdx.x];
}

__global__ void fill_kernel(const int* __restrict__ src, const int* __restrict__ dst,
                            const float* __restrict__ dinv,
                            const int* __restrict__ rowp, int* __restrict__ fill,
                            uint2* __restrict__ edges, int E) {
    int e = blockIdx.x * blockDim.x + threadIdx.x;
    if (e >= E) return;
    int s = src[e], d = dst[e];
    int pos = rowp[d] + atomicAdd(&fill[d], 1);
    edges[pos] = make_uint2((unsigned)s, __float_as_uint(dinv[s] * dinv[d]));
}

__global__ void self_kernel(const int* __restrict__ cnt, const int* __restrict__ rowp,
                            const float* __restrict__ dinv, uint2* __restrict__ edges, int n) {
    int i = blockIdx.x * blockDim.x + threadIdx.x;
    if (i >= n) return;
    float dv = dinv[i];
    edges[rowp[i] + cnt[i]] = make_uint2((unsigned)i, __float_as_uint(dv * dv));
}

// ---------------- weight / input prep ----------------

// Wt[n*K + k] = bf16(W[k*N + n])
__global__ void wt_kernel(const float* __restrict__ W, unsigned short* __restrict__ Wt,
                          int K, int N) {
    int id = blockIdx.x * blockDim.x + threadIdx.x;
    if (id >= K * N) return;
    int k = id / N, n = id % N;
    Wt[n * K + k] = (unsigned short)bf16rne(W[id]);
}

__global__ void cvt_bf16_kernel(const float* __restrict__ in, unsigned short* __restrict__ out,
                                int n4) {
    int i = blockIdx.x * blockDim.x + threadIdx.x;
    if (i >= n4) return;
    float4 v = ((const float4*)in)[i];
    uint2 o;
    o.x = bf16rne(v.x) | (bf16rne(v.y) << 16);
    o.y = bf16rne(v.z) | (bf16rne(v.w) << 16);
    ((uint2*)out)[i] = o;
}

// ---------------- MFMA GEMM ----------------

// C[M,Nc] = A[M,K] @ W[K,Nc] (+bias,relu).  A bf16 row-major, Wt bf16 [Nc][K].
// 128x128 block tile, 4 waves, each 4x4 tiles of 16x16x32 MFMA. K%32==0.
__global__ __launch_bounds__(256) void gemm_mfma_kernel(
    const unsigned short* __restrict__ A, const unsigned short* __restrict__ Wt,
    const float* __restrict__ bias, void* __restrict__ C,
    int M, int K, int Nc, int doBias, int doRelu, int outBf16) {
    __shared__ unsigned short Ab[128 * 32];   // [row][k] packed, 8 KB
    __shared__ unsigned short Bb[128 * 32];   // [col][k] packed, 8 KB
    int tid = threadIdx.x;
    int l = tid & 63, w = tid >> 6;
    int row0 = blockIdx.y * 128, col0 = blockIdx.x * 128;

    f32x4 acc[4][4];
#pragma unroll
    for (int i = 0; i < 4; i++)
#pragma unroll
        for (int j = 0; j < 4; j++) acc[i][j] = (f32x4){0.f, 0.f, 0.f, 0.f};

    // staging: thread handles 16B slot (tid + h*256); slot = r*4 + q
    const unsigned short* gA[2];
    const unsigned short* gB[2];
    unsigned short* lA[2];
    unsigned short* lB[2];
#pragma unroll
    for (int h = 0; h < 2; h++) {
        int slot = tid + h * 256;
        int r = slot >> 2, q = slot & 3;
        int ar = row0 + r; if (ar > M - 1) ar = M - 1;
        int bn = col0 + r; if (bn > Nc - 1) bn = Nc - 1;
        gA[h] = A + (size_t)ar * K + q * 8;
        gB[h] = Wt + (size_t)bn * K + q * 8;
        lA[h] = Ab + (size_t)(w * 64 + h * 256) * 8;   // wave-uniform base
        lB[h] = Bb + (size_t)(w * 64 + h * 256) * 8;
    }

    // fragment read pointers (constant across K iters: same LDS tile reused)
    int q4 = l >> 4, m16 = l & 15;
    const unsigned short* ap[4];
    const unsigned short* bp[4];
#pragma unroll
    for (int i = 0; i < 4; i++) {
        int rA = (w & 1) * 64 + i * 16 + m16;
        int rB = (w >> 1) * 64 + i * 16 + m16;
        ap[i] = Ab + rA * 32 + q4 * 8;
        bp[i] = Bb + rB * 32 + q4 * 8;
    }

    for (int k0 = 0; k0 < K; k0 += 32) {
        __syncthreads();                       // prior reads done before overwrite
#pragma unroll
        for (int h = 0; h < 2; h++) {
            stage16(gA[h] + k0, lA[h]);
            stage16(gB[h] + k0, lB[h]);
        }
        __syncthreads();                       // staging complete
        bf16x8 af[4], bfr[4];
#pragma unroll
        for (int i = 0; i < 4; i++) af[i] = *(const bf16x8*)ap[i];
#pragma unroll
        for (int j = 0; j < 4; j++) bfr[j] = *(const bf16x8*)bp[j];
#pragma unroll
        for (int i = 0; i < 4; i++)
#pragma unroll
            for (int j = 0; j < 4; j++)
                acc[i][j] = __builtin_amdgcn_mfma_f32_16x16x32_bf16(af[i], bfr[j],
                                                                    acc[i][j], 0, 0, 0);
    }

    // epilogue: C/D layout col=lane&15, row=quad*4+reg  [m89/m91]
#pragma unroll
    for (int j = 0; j < 4; j++) {
        int gc = col0 + (w >> 1) * 64 + j * 16 + m16;
        if (gc >= Nc) continue;
        float bv = doBias ? bias[gc] : 0.f;
#pragma unroll
        for (int i = 0; i < 4; i++) {
            int gr0 = row0 + (w & 1) * 64 + i * 16 + q4 * 4;
            f32x4 v = acc[i][j];
#pragma unroll
            for (int reg = 0; reg < 4; reg++) {
                int gr = gr0 + reg;
                if (gr >= M) continue;
                float x = v[reg] + bv;
                if (doRelu) x = fmaxf(x, 0.f);
                size_t off = (size_t)gr * Nc + gc;
                if (outBf16) ((unsigned short*)C)[off] = (unsigned short)bf16rne(x);
                else ((float*)C)[off] = x;
            }
        }
    }
}

// out[m] = dot(A[m,0:128], w[0:128])  A bf16, one wave per row
__global__ void gemv128_bf16_kernel(const unsigned short* __restrict__ A,
                                    const float* __restrict__ w,
                                    float* __restrict__ out, int M) {
    int wid = (blockIdx.x * blockDim.x + threadIdx.x) >> 6;
    int lane = threadIdx.x & 63;
    if (wid >= M) return;
    const unsigned short* a = A + (size_t)wid * 128;
    float a0 = __uint_as_float((unsigned)a[lane] << 16);
    float a1 = __uint_as_float((unsigned)a[lane + 64] << 16);
    float s = a0 * w[lane] + a1 * w[lane + 64];
#pragma unroll
    for (int off = 32; off > 0; off >>= 1) s += __shfl_down(s, off);
    if (lane == 0) out[wid] = s;
}

// ---------------- aggregation ----------------

// One WAVE per node, bf16 rows, fp32 accumulate. Lane fl holds feats [4fl,4fl+4).
// nvec==32: two edge-groups per wave. Edges (src,weight) uniform-loaded.
__global__ __launch_bounds__(256) void agg_bf16_kernel(
    const unsigned* __restrict__ in, const int* __restrict__ rowp,
    const int* __restrict__ cnt, const uint2* __restrict__ edges,
    const float* __restrict__ bias, void* __restrict__ out,
    int nvec, int n_nodes, int doBias, int doRelu, int outBf16) {
    int node = blockIdx.x * 4 + (threadIdx.x >> 6);
    if (node >= n_nodes) return;
    int lane = threadIdx.x & 63;
    int G, g, fl;
    if (nvec == 32) { G = 2; g = lane >> 5; fl = lane & 31; }
    else            { G = 1; g = 0; fl = lane; if (lane >= nvec) return; }

    const uint2* in2 = (const uint2*)in;
    float4 a0 = make_float4(0.f, 0.f, 0.f, 0.f);
    float4 a1 = a0, a2 = a0, a3 = a0;

    int c = cnt[node] + 1;
    int s0 = rowp[node];

    int j = g;
    for (; j + 3 * G < c; j += 4 * G) {
        uint2 e0 = edges[s0 + j];
        uint2 e1 = edges[s0 + j + G];
        uint2 e2 = edges[s0 + j + 2 * G];
        uint2 e3 = edges[s0 + j + 3 * G];
        uint2 p0 = in2[(size_t)e0.x * nvec + fl];
        uint2 p1 = in2[(size_t)e1.x * nvec + fl];
        uint2 p2 = in2[(size_t)e2.x * nvec + fl];
        uint2 p3 = in2[(size_t)e3.x * nvec + fl];
        float w0 = __uint_as_float(e0.y), w1 = __uint_as_float(e1.y);
        float w2 = __uint_as_float(e2.y), w3 = __uint_as_float(e3.y);
        a0.x += w0 * __uint_as_float(p0.x << 16);
        a0.y += w0 * __uint_as_float(p0.x & 0xffff0000u);
        a0.z += w0 * __uint_as_float(p0.y << 16);
        a0.w += w0 * __uint_as_float(p0.y & 0xffff0000u);
        a1.x += w1 * __uint_as_float(p1.x << 16);
        a1.y += w1 * __uint_as_float(p1.x & 0xffff0000u);
        a1.z += w1 * __uint_as_float(p1.y << 16);
        a1.w += w1 * __uint_as_float(p1.y & 0xffff0000u);
        a2.x += w2 * __uint_as_float(p2.x << 16);
        a2.y += w2 * __uint_as_float(p2.x & 0xffff0000u);
        a2.z += w2 * __uint_as_float(p2.y << 16);
        a2.w += w2 * __uint_as_float(p2.y & 0xffff0000u);
        a3.x += w3 * __uint_as_float(p3.x << 16);
        a3.y += w3 * __uint_as_float(p3.x & 0xffff0000u);
        a3.z += w3 * __uint_as_float(p3.y << 16);
        a3.w += w3 * __uint_as_float(p3.y & 0xffff0000u);
    }
    for (; j < c; j += G) {
        uint2 e = edges[s0 + j];
        uint2 p = in2[(size_t)e.x * nvec + fl];
        float ww = __uint_as_float(e.y);
        a0.x += ww * __uint_as_float(p.x << 16);
        a0.y += ww * __uint_as_float(p.x & 0xffff0000u);
        a0.z += ww * __uint_as_float(p.y << 16);
        a0.w += ww * __uint_as_float(p.y & 0xffff0000u);
    }

    a0.x = (a0.x + a1.x) + (a2.x + a3.x);
    a0.y = (a0.y + a1.y) + (a2.y + a3.y);
    a0.z = (a0.z + a1.z) + (a2.z + a3.z);
    a0.w = (a0.w + a1.w) + (a2.w + a3.w);

    if (nvec == 32) {
        a0.x += __shfl_down(a0.x, 32);
        a0.y += __shfl_down(a0.y, 32);
        a0.z += __shfl_down(a0.z, 32);
        a0.w += __shfl_down(a0.w, 32);
        if (lane >= 32) return;
    }

    if (doBias) {
        float4 bb = ((const float4*)bias)[fl];
        a0.x += bb.x; a0.y += bb.y; a0.z += bb.z; a0.w += bb.w;
    }
    if (doRelu) {
        a0.x = fmaxf(a0.x, 0.f); a0.y = fmaxf(a0.y, 0.f);
        a0.z = fmaxf(a0.z, 0.f); a0.w = fmaxf(a0.w, 0.f);
    }
    if (outBf16) {
        uint2 o;
        o.x = bf16rne(a0.x) | (bf16rne(a0.y) << 16);
        o.y = bf16rne(a0.z) | (bf16rne(a0.w) << 16);
        ((uint2*)out)[(size_t)node * nvec + fl] = o;
    } else {
        ((float4*)out)[(size_t)node * nvec + fl] = a0;
    }
}

// width-1 aggregation, fp32: one thread per node
__global__ void agg1_kernel(const float* __restrict__ in, const int* __restrict__ rowp,
                            const int* __restrict__ cnt, const uint2* __restrict__ edges,
                            const float* __restrict__ bias, float* __restrict__ out,
                            int n_nodes, int doRelu) {
    int n = blockIdx.x * blockDim.x + threadIdx.x;
    if (n >= n_nodes) return;
    float acc = 0.f;
    int s0 = rowp[n];
    int c = cnt[n] + 1;
    for (int j = 0; j < c; j++) {
        uint2 e = edges[s0 + j];
        acc += __uint_as_float(e.y) * in[e.x];
    }
    acc += bias[0];
    if (doRelu) acc = fmaxf(acc, 0.f);
    out[n] = acc;
}

// ---------------- host launcher ----------------

extern "C" void kernel_launch(void* const* d_in, const int* in_sizes, int n_in,
                              void* d_out, int out_size, void* d_ws, size_t ws_size,
                              hipStream_t stream) {
    const float* x = (const float*)d_in[0];
    const int* ei = (const int*)d_in[1];
    const int Nn = in_sizes[0] / 128;      // 50000
    const int E = in_sizes[1] / 2;         // 800000
    const int* src = ei;
    const int* dst = ei + E;

    char* ws = (char*)d_ws;
    size_t off = 0;
    auto alloc = [&](size_t bytes) -> char* {
        char* p = ws + off;
        off = (off + bytes + 255) & ~(size_t)255;
        return p;
    };
    int* cnt = (int*)alloc((size_t)Nn * 4);
    int* fill = (int*)alloc((size_t)Nn * 4);
    int* rowp = (int*)alloc((size_t)Nn * 4);
    int* bsums = (int*)alloc(1024);
    float* dinv = (float*)alloc((size_t)Nn * 4);
    uint2* edges = (uint2*)alloc((size_t)(E + Nn) * 8);
    unsigned short* T = (unsigned short*)alloc((size_t)Nn * 256 * 2);   // bf16 temp
    unsigned short* H = (unsigned short*)alloc((size_t)Nn * 256 * 2);   // bf16 act
    unsigned short* Bx = (unsigned short*)alloc((size_t)Nn * 128 * 2);  // bf16 input
    float* F = (float*)alloc((size_t)Nn * 4);                            // width-1 fp32
    unsigned short* Wts = (unsigned short*)alloc((size_t)400000 * 2);    // all Wt
    (void)ws_size;

    const int dims[9][2] = {{128,128},{128,192},{192,256},{256,256},{256,256},
                            {256,256},{256,192},{192,128},{128,1}};
    unsigned short* Wt[8];
    {
        size_t o = 0;
        for (int i = 0; i < 8; i++) { Wt[i] = Wts + o; o += (size_t)dims[i][0] * dims[i][1]; }
    }

    int nbN = (Nn + TPB - 1) / TPB;
    int nbE = (E + TPB - 1) / TPB;

    // ---- graph prep ----
    zero_int_kernel<<<nbN, TPB, 0, stream>>>(cnt, Nn);
    zero_int_kernel<<<nbN, TPB, 0, stream>>>(fill, Nn);
    count_kernel<<<nbE, TPB, 0, stream>>>(dst, cnt, E);
    dinv_kernel<<<nbN, TPB, 0, stream>>>(cnt, dinv, Nn);
    scan1_kernel<<<nbN, TPB, 0, stream>>>(cnt, rowp, bsums, Nn);
    scan2_kernel<<<1, TPB, 0, stream>>>(bsums, nbN);
    scan3_kernel<<<nbN, TPB, 0, stream>>>(rowp, bsums, Nn);
    fill_kernel<<<nbE, TPB, 0, stream>>>(src, dst, dinv, rowp, fill, edges, E);
    self_kernel<<<nbN, TPB, 0, stream>>>(cnt, rowp, dinv, edges, Nn);

    // ---- weight transpose + input convert ----
    for (int i = 0; i < 8; i++) {
        int K = dims[i][0], N = dims[i][1];
        wt_kernel<<<(K * N + TPB - 1) / TPB, TPB, 0, stream>>>(
            (const float*)d_in[2 + 2 * i], Wt[i], K, N);
    }
    cvt_bf16_kernel<<<(Nn * 32 + TPB - 1) / TPB, TPB, 0, stream>>>(x, Bx, Nn * 32);

    int aggBlocks = (Nn + 3) / 4;

    auto gemm = [&](const unsigned short* A, int i, void* C, int K, int Nc,
                    int doBias, int doRelu) {
        const float* b = (const float*)d_in[3 + 2 * i];
        dim3 grid((Nc + 127) / 128, (Nn + 127) / 128);
        gemm_mfma_kernel<<<grid, 256, 0, stream>>>(A, Wt[i], b, C, Nn, K, Nc,
                                                   doBias, doRelu, 1);
    };
    auto agg = [&](const unsigned short* in, void* outp, int w, int i, int doBias,
                   int doRelu) {
        const float* b = doBias ? (const float*)d_in[3 + 2 * i] : (const float*)d_in[3];
        agg_bf16_kernel<<<aggBlocks, 256, 0, stream>>>((const unsigned*)in, rowp, cnt,
                                                       edges, b, outp, w / 4, Nn,
                                                       doBias, doRelu, 1);
    };

    // L0: t = Bx@W0 -> T; h1 = Â t + b0 relu -> H
    gemm(Bx, 0, T, 128, 128, 0, 0);
    agg(T, H, 128, 0, 1, 1);
    // L1 aggFirst: u = Â h1 -> T; h2 = u@W1+b1 relu -> H
    agg(H, T, 128, 1, 0, 0);
    gemm(T, 1, H, 128, 192, 1, 1);
    // L2 aggFirst: u = Â h2 -> T; h3 = u@W2+b2 relu -> H
    agg(H, T, 192, 2, 0, 0);
    gemm(T, 2, H, 192, 256, 1, 1);
    // L3: t = h3@W3 -> T; h4 = Â t + b3 relu -> H
    gemm(H, 3, T, 256, 256, 0, 0);
    agg(T, H, 256, 3, 1, 1);
    // L4: t = h4@W4 -> T; h5 = Â t + b4 (no relu) -> H
    gemm(H, 4, T, 256, 256, 0, 0);
    agg(T, H, 256, 4, 1, 0);
    // L5: t = h5@W5 -> T; h6 = Â t + b5 relu -> H
    gemm(H, 5, T, 256, 256, 0, 0);
    agg(T, H, 256, 5, 1, 1);
    // L6: t = h6@W6 -> T; h7 = Â t + b6 relu -> H
    gemm(H, 6, T, 256, 192, 0, 0);
    agg(T, H, 192, 6, 1, 1);
    // L7: t = h7@W7 -> T; h8 = Â t + b7 relu -> H
    gemm(H, 7, T, 192, 128, 0, 0);
    agg(T, H, 128, 7, 1, 1);
    // L8: s = h8@W8 -> F; out = Â s + b8
    gemv128_bf16_kernel<<<(Nn + 3) / 4, 256, 0, stream>>>(H, (const float*)d_in[2 + 16],
                                                          F, Nn);
    agg1_kernel<<<nbN, TPB, 0, stream>>>(F, rowp, cnt, edges, (const float*)d_in[3 + 16],
                                         (float*)d_out, Nn, 0);
}